// Round 7
// baseline (333.613 us; speedup 1.0000x reference)
//
#include <hip/hip_runtime.h>
#include <math.h>

// GCN 2-layer, N nodes, E edges, 64 -> 64 -> 32 channels.
// R7: divergence-free gathers.
//  gather1: full wave per node (uniform loop bounds), two 32-lane halves work
//  alternate 8-edge batches -> 16 gathered rows in flight, no exec-mask waste.
//  g2pool: edge-parallel per-bucket (ebkt keeps dl bits), dinv[dst] from LDS,
//  fused mean-pool; zero per-node divergence, perfect balance.
// Front-end (binA/bscan/compact2) and VGPR-W GEMMs from R6.

#define C1 64
#define C2 32
#define CHUNK 8192
#define BNODES 128

__device__ __forceinline__ unsigned short f2bf(float f) {
    unsigned u = __float_as_uint(f);
    u = (u + 0x7FFFu + ((u >> 16) & 1u)) >> 16;
    return (unsigned short)u;
}
__device__ __forceinline__ float bf2f(unsigned short u) {
    return __uint_as_float((unsigned)u << 16);
}

// ---- binA: per-chunk LDS counting sort by bucket (dst>>7). Coalesced IO. ----
__global__ __launch_bounds__(256) void binA_kernel(
    const int* __restrict__ src, const int* __restrict__ dst, int E, int NB, int NC,
    unsigned* __restrict__ binned, int* __restrict__ startsT,
    int* __restrict__ countsT, unsigned* __restrict__ btot) {
    __shared__ unsigned hist[1024];
    __shared__ unsigned scan[1024];
    __shared__ unsigned part[256];
    __shared__ unsigned stage[CHUNK];
    int t = threadIdx.x;
    int c = blockIdx.x;
    int e0 = c * CHUNK;
    int len = min(CHUNK, E - e0);
    for (int i = t; i < 1024; i += 256) hist[i] = 0;
    __syncthreads();
    for (int i = t; i < len; i += 256)
        atomicAdd(&hist[dst[e0 + i] >> 7], 1u);
    __syncthreads();
    unsigned v0 = hist[4 * t], v1 = hist[4 * t + 1], v2 = hist[4 * t + 2], v3 = hist[4 * t + 3];
    unsigned sum = v0 + v1 + v2 + v3;
    part[t] = sum;
    __syncthreads();
    for (int st = 1; st < 256; st <<= 1) {
        unsigned a = part[t];
        unsigned bl = (t >= st) ? part[t - st] : 0u;
        __syncthreads();
        part[t] = a + bl;
        __syncthreads();
    }
    unsigned base = part[t] - sum;
    scan[4 * t]     = base;
    scan[4 * t + 1] = base + v0;
    scan[4 * t + 2] = base + v0 + v1;
    scan[4 * t + 3] = base + v0 + v1 + v2;
    __syncthreads();
    for (int b = t; b < NB; b += 256) {
        unsigned cnt = hist[b];
        countsT[b * NC + c] = (int)cnt;
        startsT[b * NC + c] = e0 + (int)scan[b];
        if (cnt) atomicAdd(&btot[b], cnt);
    }
    for (int i = t; i < len; i += 256) {
        int s = src[e0 + i];
        int d = dst[e0 + i];
        unsigned pos = atomicAdd(&scan[d >> 7], 1u);
        stage[pos] = ((unsigned)(d & 127) << 17) | (unsigned)s;
    }
    __syncthreads();
    for (int i = t; i < len; i += 256) binned[e0 + i] = stage[i];
}

// ---- bscan: exclusive scan of per-bucket totals -> bstart[NB+1] ----
__global__ __launch_bounds__(256) void bscan_kernel(const unsigned* __restrict__ btot,
                                                    int* __restrict__ bstart, int NB) {
    __shared__ unsigned part[256];
    int t = threadIdx.x;
    unsigned v[4];
    unsigned sum = 0;
    for (int i = 0; i < 4; ++i) {
        int idx = 4 * t + i;
        v[i] = (idx < NB) ? btot[idx] : 0u;
        sum += v[i];
    }
    part[t] = sum;
    __syncthreads();
    for (int st = 1; st < 256; st <<= 1) {
        unsigned a = part[t];
        unsigned bl = (t >= st) ? part[t - st] : 0u;
        __syncthreads();
        part[t] = a + bl;
        __syncthreads();
    }
    unsigned run = part[t] - sum;
    for (int i = 0; i < 4; ++i) {
        int idx = 4 * t + i;
        if (idx < NB) bstart[idx] = (int)run;
        run += v[i];
    }
    if (t == 255) bstart[NB] = (int)run;
}

// ---- compact2: per-bucket per-node counting sort; fused deg->dinv + off ----
// ebkt keeps full (dl<<17)|src entries (g2pool needs dl).
__global__ __launch_bounds__(256) void compact2_kernel(
    const unsigned* __restrict__ binned, const int* __restrict__ startsT,
    const int* __restrict__ countsT, const int* __restrict__ bstart,
    int N, int NC, int E, unsigned* __restrict__ ebkt, int* __restrict__ off,
    float* __restrict__ dinv) {
    __shared__ unsigned cnt[BNODES];
    __shared__ unsigned sc[BNODES];
    __shared__ unsigned cur[BNODES];
    __shared__ int sS[256], sC[256];
    int t = threadIdx.x;
    int b = blockIdx.x;
    if (t < BNODES) cnt[t] = 0;
    if (t < NC) { sS[t] = startsT[b * NC + t]; sC[t] = countsT[b * NC + t]; }
    __syncthreads();
    int lane = t & 63, w = t >> 6;
    for (int c = w; c < NC; c += 4) {
        int s0 = sS[c], len = sC[c];
        for (int o = lane; o < len; o += 64)
            atomicAdd(&cnt[binned[s0 + o] >> 17], 1u);
    }
    __syncthreads();
    if (t < BNODES) sc[t] = cnt[t];
    __syncthreads();
    for (int st = 1; st < BNODES; st <<= 1) {
        unsigned v = 0;
        if (t < BNODES) { v = sc[t]; if (t >= st) v += sc[t - st]; }
        __syncthreads();
        if (t < BNODES) sc[t] = v;
        __syncthreads();
    }
    int dbase = bstart[b];
    if (t < BNODES) {
        unsigned excl = sc[t] - cnt[t];
        cur[t] = excl;
        int n = b * BNODES + t;
        if (n < N) {
            off[n] = dbase + (int)excl;
            dinv[n] = rsqrtf((float)cnt[t] + 1.0f);
        }
    }
    if (b == 0 && t == 0) off[N] = E;
    __syncthreads();
    for (int c = w; c < NC; c += 4) {
        int s0 = sS[c], len = sC[c];
        for (int o = lane; o < len; o += 64) {
            unsigned ent = binned[s0 + o];
            unsigned pos = atomicAdd(&cur[ent >> 17], 1u);
            ebkt[dbase + (int)pos] = ent;  // keep dl bits
        }
    }
}

// ---- gemm1: xws = bf16(dinv * (x @ W1)); W in VGPRs, broadcast LDS reads ----
__global__ __launch_bounds__(256) void gemm1_kernel(
    const float* __restrict__ x, const float* __restrict__ W,
    const float* __restrict__ dinv, unsigned short* __restrict__ xws, int N) {
    __shared__ __align__(16) float stage[4][256];
    int t = threadIdx.x;
    int lane = t & 63;
    int w = t >> 6;
    float wv[64];
#pragma unroll
    for (int k = 0; k < 64; ++k) wv[k] = W[k * 64 + lane];
    float* buf = stage[w];
    int wave = (blockIdx.x * blockDim.x + t) >> 6;
    int nw = (gridDim.x * blockDim.x) >> 6;
    for (int g0 = wave * 4; g0 < N; g0 += nw * 4) {
        int nrem = N - g0;
        int nfl = min(nrem * 16, 64);
        const float4* xr = (const float4*)(x + (size_t)g0 * C1);
        float4 v = make_float4(0.f, 0.f, 0.f, 0.f);
        if (lane < nfl) v = xr[lane];
        ((float4*)buf)[lane] = v;
        const float4* b0 = (const float4*)(buf);
        const float4* b1p = (const float4*)(buf + 64);
        const float4* b2p = (const float4*)(buf + 128);
        const float4* b3p = (const float4*)(buf + 192);
        float a0 = 0.f, a1 = 0.f, a2 = 0.f, a3 = 0.f;
#pragma unroll
        for (int j = 0; j < 16; ++j) {
            float4 x0 = b0[j], x1 = b1p[j], x2 = b2p[j], x3 = b3p[j];
            float w0 = wv[4 * j], w1 = wv[4 * j + 1], w2 = wv[4 * j + 2], w3 = wv[4 * j + 3];
            a0 += x0.x * w0 + x0.y * w1 + x0.z * w2 + x0.w * w3;
            a1 += x1.x * w0 + x1.y * w1 + x1.z * w2 + x1.w * w3;
            a2 += x2.x * w0 + x2.y * w1 + x2.z * w2 + x2.w * w3;
            a3 += x3.x * w0 + x3.y * w1 + x3.z * w2 + x3.w * w3;
        }
        xws[(size_t)g0 * C1 + lane] = f2bf(dinv[g0] * a0);
        if (nrem > 1) xws[(size_t)(g0 + 1) * C1 + lane] = f2bf(dinv[g0 + 1] * a1);
        if (nrem > 2) xws[(size_t)(g0 + 2) * C1 + lane] = f2bf(dinv[g0 + 2] * a2);
        if (nrem > 3) xws[(size_t)(g0 + 3) * C1 + lane] = f2bf(dinv[g0 + 3] * a3);
    }
}

// ---- gather1: full wave per node; halves take alternate 8-edge batches ----
__global__ __launch_bounds__(256) void gather1_kernel(
    const ushort2* __restrict__ xws2, const unsigned* __restrict__ ep,
    const int* __restrict__ off, const float* __restrict__ dinv,
    float2* __restrict__ out1, int N) {
    int t = threadIdx.x;
    int lane = t & 63;
    int c2 = lane & 31;
    int half = lane >> 5;
    int wave = (blockIdx.x * blockDim.x + t) >> 6;
    int nwaves = (gridDim.x * blockDim.x) >> 6;
    int per = (N + nwaves - 1) / nwaves;
    int n0 = wave * per;
    int n1 = min(N, n0 + per);
    for (int n = n0; n < n1; ++n) {
        int e = off[n], e1 = off[n + 1];
        float a0 = 0.f, a1 = 0.f;
        while (e + 15 < e1) {  // uniform across wave: no exec-mask waste
            int eb = e + (half << 3);
            unsigned s0 = ep[eb] & 0x1FFFFu,     s1 = ep[eb + 1] & 0x1FFFFu;
            unsigned s2 = ep[eb + 2] & 0x1FFFFu, s3 = ep[eb + 3] & 0x1FFFFu;
            unsigned s4 = ep[eb + 4] & 0x1FFFFu, s5 = ep[eb + 5] & 0x1FFFFu;
            unsigned s6 = ep[eb + 6] & 0x1FFFFu, s7 = ep[eb + 7] & 0x1FFFFu;
            ushort2 v0 = xws2[(size_t)s0 * 32 + c2];
            ushort2 v1 = xws2[(size_t)s1 * 32 + c2];
            ushort2 v2 = xws2[(size_t)s2 * 32 + c2];
            ushort2 v3 = xws2[(size_t)s3 * 32 + c2];
            ushort2 v4 = xws2[(size_t)s4 * 32 + c2];
            ushort2 v5 = xws2[(size_t)s5 * 32 + c2];
            ushort2 v6 = xws2[(size_t)s6 * 32 + c2];
            ushort2 v7 = xws2[(size_t)s7 * 32 + c2];
            a0 += bf2f(v0.x) + bf2f(v1.x) + bf2f(v2.x) + bf2f(v3.x)
                + bf2f(v4.x) + bf2f(v5.x) + bf2f(v6.x) + bf2f(v7.x);
            a1 += bf2f(v0.y) + bf2f(v1.y) + bf2f(v2.y) + bf2f(v3.y)
                + bf2f(v4.y) + bf2f(v5.y) + bf2f(v6.y) + bf2f(v7.y);
            e += 16;
        }
        int rem = e1 - e;  // 0..15
        int myrem = half ? (rem > 8 ? rem - 8 : 0) : (rem < 8 ? rem : 8);
        int myoff = e + (half << 3);
        for (int j = 0; j < myrem; ++j) {
            unsigned s = ep[myoff + j] & 0x1FFFFu;
            ushort2 v = xws2[(size_t)s * 32 + c2];
            a0 += bf2f(v.x);
            a1 += bf2f(v.y);
        }
        a0 += __shfl_down(a0, 32);
        a1 += __shfl_down(a1, 32);
        if (half == 0) {
            float di = dinv[n];
            ushort2 sv = xws2[(size_t)n * 32 + c2];
            out1[(size_t)n * 32 + c2] =
                make_float2(di * (a0 + di * bf2f(sv.x)), di * (a1 + di * bf2f(sv.y)));
        }
    }
}

// ---- gemm2: hws = bf16(dinv * (relu(out1 + b1) @ W2)); W2 in VGPRs ----
__global__ __launch_bounds__(256) void gemm2_kernel(
    const float* __restrict__ out1, const float* __restrict__ W2,
    const float* __restrict__ b1, const float* __restrict__ dinv,
    unsigned short* __restrict__ hws, int N) {
    __shared__ __align__(16) float stage[4][256];
    int t = threadIdx.x;
    int lane = t & 63;
    int w = t >> 6;
    int c = lane & 31;
    int half = lane >> 5;
    float wv[64];
#pragma unroll
    for (int k = 0; k < 64; ++k) wv[k] = W2[k * 32 + c];
    float4 bc = ((const float4*)b1)[lane & 15];
    float* buf = stage[w];
    int wave = (blockIdx.x * blockDim.x + t) >> 6;
    int nw = (gridDim.x * blockDim.x) >> 6;
    for (int g0 = wave * 4; g0 < N; g0 += nw * 4) {
        int nrem = N - g0;
        int nfl = min(nrem * 16, 64);
        const float4* xr = (const float4*)(out1 + (size_t)g0 * C1);
        float4 v = make_float4(0.f, 0.f, 0.f, 0.f);
        if (lane < nfl) v = xr[lane];
        v.x = fmaxf(v.x + bc.x, 0.f);
        v.y = fmaxf(v.y + bc.y, 0.f);
        v.z = fmaxf(v.z + bc.z, 0.f);
        v.w = fmaxf(v.w + bc.w, 0.f);
        ((float4*)buf)[lane] = v;
        int r0 = 2 * half;
        const float4* bx0 = (const float4*)(buf + r0 * 64);
        const float4* bx1 = (const float4*)(buf + (r0 + 1) * 64);
        float a0 = 0.f, a1 = 0.f;
#pragma unroll
        for (int j = 0; j < 16; ++j) {
            float4 x0 = bx0[j], x1 = bx1[j];
            float w0 = wv[4 * j], w1 = wv[4 * j + 1], w2 = wv[4 * j + 2], w3 = wv[4 * j + 3];
            a0 += x0.x * w0 + x0.y * w1 + x0.z * w2 + x0.w * w3;
            a1 += x1.x * w0 + x1.y * w1 + x1.z * w2 + x1.w * w3;
        }
        int n0 = g0 + r0;
        if (n0 < N)     hws[(size_t)n0 * C2 + c]       = f2bf(dinv[n0] * a0);
        if (n0 + 1 < N) hws[(size_t)(n0 + 1) * C2 + c] = f2bf(dinv[n0 + 1] * a1);
    }
}

// ---- g2pool: edge-parallel layer-2 aggregation + fused mean-pool ----
// Block = half-bucket. pooled += sum_e dinv[dst_e]*hws[src_e] + self terms.
__global__ __launch_bounds__(256) void g2pool_kernel(
    const ushort2* __restrict__ hws2, const unsigned* __restrict__ ep,
    const int* __restrict__ bstart, const float* __restrict__ dinv,
    float* __restrict__ pooled, int N) {
    __shared__ float dl_dinv[BNODES];
    __shared__ float ps[32];
    int t = threadIdx.x;
    int b = blockIdx.x >> 1;
    int part = blockIdx.x & 1;
    int nbase = b * BNODES;
    int nloc = min(BNODES, N - nbase);
    if (t < 32) ps[t] = 0.f;
    if (t < BNODES) dl_dinv[t] = (t < nloc) ? dinv[nbase + t] : 0.f;
    __syncthreads();
    int es = bstart[b], ee = bstart[b + 1];
    int len = ee - es;
    int e_lo = es + ((len * part) >> 1);
    int e_hi = es + ((len * (part + 1)) >> 1);
    int lane = t & 63;
    int slot = t >> 4;   // 0..15
    int c2 = t & 15;
    float p0 = 0.f, p1 = 0.f;
    for (int e = e_lo + slot * 8; e < e_hi; e += 128) {
        int m = min(8, e_hi - e);
        int idx = e + (c2 & 7);
        unsigned ent = (idx < e_hi) ? ep[idx] : 0u;
#pragma unroll
        for (int j = 0; j < 8; ++j) {
            unsigned ej = __shfl(ent, (lane & 48) | j);
            if (j < m) {
                ushort2 v = hws2[(size_t)(ej & 0x1FFFFu) * 16 + c2];
                float dd = dl_dinv[ej >> 17];
                p0 += dd * bf2f(v.x);
                p1 += dd * bf2f(v.y);
            }
        }
    }
    // self-loop terms: dinv[n]^2 * hws[n], split rows across the block (part 0 only)
    if (part == 0) {
        for (int r = t >> 4; r < nloc; r += 16) {
            float di = dl_dinv[r];
            ushort2 sv = hws2[(size_t)(nbase + r) * 16 + c2];
            p0 += di * di * bf2f(sv.x);
            p1 += di * di * bf2f(sv.y);
        }
    }
    p0 += __shfl_down(p0, 32); p1 += __shfl_down(p1, 32);
    p0 += __shfl_down(p0, 16); p1 += __shfl_down(p1, 16);
    if (lane < 16) {
        atomicAdd(&ps[2 * c2], p0);
        atomicAdd(&ps[2 * c2 + 1], p1);
    }
    __syncthreads();
    if (t < 32) atomicAdd(&pooled[t], ps[t]);
}

// ---- final: mean + b2, log_softmax over 32 classes ----
__global__ void final_kernel(const float* __restrict__ pooled,
                             const float* __restrict__ b2, int N,
                             float* __restrict__ out) {
    int c = threadIdx.x & 31;
    float v = pooled[c] / (float)N + b2[c];
    float m = v;
    for (int off = 16; off; off >>= 1) m = fmaxf(m, __shfl_xor(m, off));
    float s = __expf(v - m);
    for (int off = 16; off; off >>= 1) s += __shfl_xor(s, off);
    if (threadIdx.x < 32) out[c] = v - m - logf(s);
}

extern "C" void kernel_launch(void* const* d_in, const int* in_sizes, int n_in,
                              void* d_out, int out_size, void* d_ws, size_t ws_size,
                              hipStream_t stream) {
    const float* x  = (const float*)d_in[0];
    const int*   ei = (const int*)d_in[1];
    const float* W1 = (const float*)d_in[2];
    const float* b1 = (const float*)d_in[3];
    const float* W2 = (const float*)d_in[4];
    const float* b2 = (const float*)d_in[5];
    float* out = (float*)d_out;

    int N = in_sizes[0] / C1;
    int E = in_sizes[1] / 2;
    const int* src = ei;
    const int* dst = ei + E;
    int NB = (N + BNODES - 1) / BNODES;   // 782
    int NC = (E + CHUNK - 1) / CHUNK;     // 196 (<= 256)

    char* ws = (char*)d_ws;
    size_t o = 0;
    auto alloc = [&](size_t bytes) { void* p = ws + o; o = (o + bytes + 255) & ~(size_t)255; return p; };
    unsigned*       btot    = (unsigned*)alloc((size_t)(NB + 1) * 4);
    int*            bstart  = (int*)alloc((size_t)(NB + 1) * 4);
    int*            startsT = (int*)alloc((size_t)NB * NC * 4);
    int*            countsT = (int*)alloc((size_t)NB * NC * 4);
    float*          dinv    = (float*)alloc((size_t)N * 4);
    int*            off     = (int*)alloc((size_t)(N + 1) * 4);
    float*          pooled  = (float*)alloc(32 * 4);
    unsigned*       binned  = (unsigned*)alloc((size_t)E * 4);
    unsigned*       ebkt    = (unsigned*)alloc((size_t)E * 4);
    unsigned short* xws     = (unsigned short*)alloc((size_t)N * C1 * 2);
    float*          out1    = (float*)alloc((size_t)N * C1 * 4);
    unsigned short* hws     = (unsigned short*)alloc((size_t)N * C2 * 2);

    hipMemsetAsync(btot, 0, (size_t)(NB + 1) * 4, stream);
    hipMemsetAsync(pooled, 0, 32 * 4, stream);

    binA_kernel<<<NC, 256, 0, stream>>>(src, dst, E, NB, NC, binned, startsT, countsT, btot);
    bscan_kernel<<<1, 256, 0, stream>>>(btot, bstart, NB);
    compact2_kernel<<<NB, 256, 0, stream>>>(binned, startsT, countsT, bstart, N, NC, E,
                                            ebkt, off, dinv);
    gemm1_kernel<<<1024, 256, 0, stream>>>(x, W1, dinv, xws, N);
    gather1_kernel<<<6144, 256, 0, stream>>>((const ushort2*)xws, ebkt, off, dinv,
                                             (float2*)out1, N);
    gemm2_kernel<<<1024, 256, 0, stream>>>(out1, W2, b1, dinv, hws, N);
    g2pool_kernel<<<NB * 2, 256, 0, stream>>>((const ushort2*)hws, ebkt, bstart, dinv,
                                              pooled, N);
    final_kernel<<<1, 64, 0, stream>>>(pooled, b2, N, out);
}

// Round 8
// 302.736 us; speedup vs baseline: 1.1020x; 1.1020x over previous
//
#include <hip/hip_runtime.h>
#include <math.h>

// GCN 2-layer, N nodes, E edges, 64 -> 64 -> 32 channels.
// R8: gather1 = quarter-slot (16 lanes x ushort4 = full 128B row/load), one
// node per slot, 16-edge shfl-distributed batches -> up to 64 row-loads in
// flight per wave. out1 stored bf16 (halves round-trip). g2pool, front-end,
// VGPR-W GEMMs unchanged.

#define C1 64
#define C2 32
#define CHUNK 8192
#define BNODES 128

__device__ __forceinline__ unsigned short f2bf(float f) {
    unsigned u = __float_as_uint(f);
    u = (u + 0x7FFFu + ((u >> 16) & 1u)) >> 16;
    return (unsigned short)u;
}
__device__ __forceinline__ float bf2f(unsigned short u) {
    return __uint_as_float((unsigned)u << 16);
}

// ---- binA: per-chunk LDS counting sort by bucket (dst>>7). Coalesced IO. ----
__global__ __launch_bounds__(256) void binA_kernel(
    const int* __restrict__ src, const int* __restrict__ dst, int E, int NB, int NC,
    unsigned* __restrict__ binned, int* __restrict__ startsT,
    int* __restrict__ countsT, unsigned* __restrict__ btot) {
    __shared__ unsigned hist[1024];
    __shared__ unsigned scan[1024];
    __shared__ unsigned part[256];
    __shared__ unsigned stage[CHUNK];
    int t = threadIdx.x;
    int c = blockIdx.x;
    int e0 = c * CHUNK;
    int len = min(CHUNK, E - e0);
    for (int i = t; i < 1024; i += 256) hist[i] = 0;
    __syncthreads();
    for (int i = t; i < len; i += 256)
        atomicAdd(&hist[dst[e0 + i] >> 7], 1u);
    __syncthreads();
    unsigned v0 = hist[4 * t], v1 = hist[4 * t + 1], v2 = hist[4 * t + 2], v3 = hist[4 * t + 3];
    unsigned sum = v0 + v1 + v2 + v3;
    part[t] = sum;
    __syncthreads();
    for (int st = 1; st < 256; st <<= 1) {
        unsigned a = part[t];
        unsigned bl = (t >= st) ? part[t - st] : 0u;
        __syncthreads();
        part[t] = a + bl;
        __syncthreads();
    }
    unsigned base = part[t] - sum;
    scan[4 * t]     = base;
    scan[4 * t + 1] = base + v0;
    scan[4 * t + 2] = base + v0 + v1;
    scan[4 * t + 3] = base + v0 + v1 + v2;
    __syncthreads();
    for (int b = t; b < NB; b += 256) {
        unsigned cnt = hist[b];
        countsT[b * NC + c] = (int)cnt;
        startsT[b * NC + c] = e0 + (int)scan[b];
        if (cnt) atomicAdd(&btot[b], cnt);
    }
    for (int i = t; i < len; i += 256) {
        int s = src[e0 + i];
        int d = dst[e0 + i];
        unsigned pos = atomicAdd(&scan[d >> 7], 1u);
        stage[pos] = ((unsigned)(d & 127) << 17) | (unsigned)s;
    }
    __syncthreads();
    for (int i = t; i < len; i += 256) binned[e0 + i] = stage[i];
}

// ---- bscan: exclusive scan of per-bucket totals -> bstart[NB+1] ----
__global__ __launch_bounds__(256) void bscan_kernel(const unsigned* __restrict__ btot,
                                                    int* __restrict__ bstart, int NB) {
    __shared__ unsigned part[256];
    int t = threadIdx.x;
    unsigned v[4];
    unsigned sum = 0;
    for (int i = 0; i < 4; ++i) {
        int idx = 4 * t + i;
        v[i] = (idx < NB) ? btot[idx] : 0u;
        sum += v[i];
    }
    part[t] = sum;
    __syncthreads();
    for (int st = 1; st < 256; st <<= 1) {
        unsigned a = part[t];
        unsigned bl = (t >= st) ? part[t - st] : 0u;
        __syncthreads();
        part[t] = a + bl;
        __syncthreads();
    }
    unsigned run = part[t] - sum;
    for (int i = 0; i < 4; ++i) {
        int idx = 4 * t + i;
        if (idx < NB) bstart[idx] = (int)run;
        run += v[i];
    }
    if (t == 255) bstart[NB] = (int)run;
}

// ---- compact2: per-bucket per-node counting sort; fused deg->dinv + off ----
// ebkt keeps full (dl<<17)|src entries (g2pool needs dl).
__global__ __launch_bounds__(256) void compact2_kernel(
    const unsigned* __restrict__ binned, const int* __restrict__ startsT,
    const int* __restrict__ countsT, const int* __restrict__ bstart,
    int N, int NC, int E, unsigned* __restrict__ ebkt, int* __restrict__ off,
    float* __restrict__ dinv) {
    __shared__ unsigned cnt[BNODES];
    __shared__ unsigned sc[BNODES];
    __shared__ unsigned cur[BNODES];
    __shared__ int sS[256], sC[256];
    int t = threadIdx.x;
    int b = blockIdx.x;
    if (t < BNODES) cnt[t] = 0;
    if (t < NC) { sS[t] = startsT[b * NC + t]; sC[t] = countsT[b * NC + t]; }
    __syncthreads();
    int lane = t & 63, w = t >> 6;
    for (int c = w; c < NC; c += 4) {
        int s0 = sS[c], len = sC[c];
        for (int o = lane; o < len; o += 64)
            atomicAdd(&cnt[binned[s0 + o] >> 17], 1u);
    }
    __syncthreads();
    if (t < BNODES) sc[t] = cnt[t];
    __syncthreads();
    for (int st = 1; st < BNODES; st <<= 1) {
        unsigned v = 0;
        if (t < BNODES) { v = sc[t]; if (t >= st) v += sc[t - st]; }
        __syncthreads();
        if (t < BNODES) sc[t] = v;
        __syncthreads();
    }
    int dbase = bstart[b];
    if (t < BNODES) {
        unsigned excl = sc[t] - cnt[t];
        cur[t] = excl;
        int n = b * BNODES + t;
        if (n < N) {
            off[n] = dbase + (int)excl;
            dinv[n] = rsqrtf((float)cnt[t] + 1.0f);
        }
    }
    if (b == 0 && t == 0) off[N] = E;
    __syncthreads();
    for (int c = w; c < NC; c += 4) {
        int s0 = sS[c], len = sC[c];
        for (int o = lane; o < len; o += 64) {
            unsigned ent = binned[s0 + o];
            unsigned pos = atomicAdd(&cur[ent >> 17], 1u);
            ebkt[dbase + (int)pos] = ent;  // keep dl bits
        }
    }
}

// ---- gemm1: xws = bf16(dinv * (x @ W1)); W in VGPRs, broadcast LDS reads ----
__global__ __launch_bounds__(256) void gemm1_kernel(
    const float* __restrict__ x, const float* __restrict__ W,
    const float* __restrict__ dinv, unsigned short* __restrict__ xws, int N) {
    __shared__ __align__(16) float stage[4][256];
    int t = threadIdx.x;
    int lane = t & 63;
    int w = t >> 6;
    float wv[64];
#pragma unroll
    for (int k = 0; k < 64; ++k) wv[k] = W[k * 64 + lane];
    float* buf = stage[w];
    int wave = (blockIdx.x * blockDim.x + t) >> 6;
    int nw = (gridDim.x * blockDim.x) >> 6;
    for (int g0 = wave * 4; g0 < N; g0 += nw * 4) {
        int nrem = N - g0;
        int nfl = min(nrem * 16, 64);
        const float4* xr = (const float4*)(x + (size_t)g0 * C1);
        float4 v = make_float4(0.f, 0.f, 0.f, 0.f);
        if (lane < nfl) v = xr[lane];
        ((float4*)buf)[lane] = v;
        const float4* b0 = (const float4*)(buf);
        const float4* b1p = (const float4*)(buf + 64);
        const float4* b2p = (const float4*)(buf + 128);
        const float4* b3p = (const float4*)(buf + 192);
        float a0 = 0.f, a1 = 0.f, a2 = 0.f, a3 = 0.f;
#pragma unroll
        for (int j = 0; j < 16; ++j) {
            float4 x0 = b0[j], x1 = b1p[j], x2 = b2p[j], x3 = b3p[j];
            float w0 = wv[4 * j], w1 = wv[4 * j + 1], w2 = wv[4 * j + 2], w3 = wv[4 * j + 3];
            a0 += x0.x * w0 + x0.y * w1 + x0.z * w2 + x0.w * w3;
            a1 += x1.x * w0 + x1.y * w1 + x1.z * w2 + x1.w * w3;
            a2 += x2.x * w0 + x2.y * w1 + x2.z * w2 + x2.w * w3;
            a3 += x3.x * w0 + x3.y * w1 + x3.z * w2 + x3.w * w3;
        }
        xws[(size_t)g0 * C1 + lane] = f2bf(dinv[g0] * a0);
        if (nrem > 1) xws[(size_t)(g0 + 1) * C1 + lane] = f2bf(dinv[g0 + 1] * a1);
        if (nrem > 2) xws[(size_t)(g0 + 2) * C1 + lane] = f2bf(dinv[g0 + 2] * a2);
        if (nrem > 3) xws[(size_t)(g0 + 3) * C1 + lane] = f2bf(dinv[g0 + 3] * a3);
    }
}

// ---- gather1: quarter-slot per node; 16-edge batches, ushort4 row loads ----
// out1b[n] = bf16( dinv[n]*(sum_e xws[src_e] + dinv[n]*xws[n]) )
__global__ __launch_bounds__(256) void gather1_kernel(
    const ushort4* __restrict__ xws4, const unsigned* __restrict__ ep,
    const int* __restrict__ off, const float* __restrict__ dinv,
    ushort4* __restrict__ out1b, int N) {
    int t = threadIdx.x;
    int lane = t & 63;
    int c4 = t & 15;
    int n = (blockIdx.x * 256 + t) >> 4;  // slot == node
    if (n >= N) return;
    int e0 = off[n], e1 = off[n + 1];
    float a0 = 0.f, a1 = 0.f, a2 = 0.f, a3 = 0.f;
    for (int e = e0; e < e1; e += 16) {
        int m = e1 - e;  // uniform within slot
        int idx = e + c4;
        unsigned ent = (idx < e1) ? ep[idx] : 0u;
#pragma unroll
        for (int j = 0; j < 16; ++j) {
            unsigned ej = __shfl(ent, (lane & 48) | j);
            if (j < m) {
                ushort4 v = xws4[(size_t)(ej & 0x1FFFFu) * 16 + c4];
                a0 += bf2f(v.x);
                a1 += bf2f(v.y);
                a2 += bf2f(v.z);
                a3 += bf2f(v.w);
            }
        }
    }
    float di = dinv[n];
    ushort4 sv = xws4[(size_t)n * 16 + c4];
    ushort4 o;
    o.x = f2bf(di * (a0 + di * bf2f(sv.x)));
    o.y = f2bf(di * (a1 + di * bf2f(sv.y)));
    o.z = f2bf(di * (a2 + di * bf2f(sv.z)));
    o.w = f2bf(di * (a3 + di * bf2f(sv.w)));
    out1b[(size_t)n * 16 + c4] = o;
}

// ---- gemm2: hws = bf16(dinv * (relu(out1b + b1) @ W2)); W2 in VGPRs ----
__global__ __launch_bounds__(256) void gemm2_kernel(
    const unsigned short* __restrict__ out1b, const float* __restrict__ W2,
    const float* __restrict__ b1, const float* __restrict__ dinv,
    unsigned short* __restrict__ hws, int N) {
    __shared__ __align__(16) float stage[4][256];
    int t = threadIdx.x;
    int lane = t & 63;
    int w = t >> 6;
    int c = lane & 31;
    int half = lane >> 5;
    float wv[64];
#pragma unroll
    for (int k = 0; k < 64; ++k) wv[k] = W2[k * 32 + c];
    float4 bc = ((const float4*)b1)[lane & 15];
    float* buf = stage[w];
    int wave = (blockIdx.x * blockDim.x + t) >> 6;
    int nw = (gridDim.x * blockDim.x) >> 6;
    for (int g0 = wave * 4; g0 < N; g0 += nw * 4) {
        int nrem = N - g0;
        int nfl = min(nrem * 16, 64);
        const ushort4* xr = (const ushort4*)(out1b + (size_t)g0 * C1);
        ushort4 u = make_ushort4(0, 0, 0, 0);
        if (lane < nfl) u = xr[lane];
        float4 v;
        v.x = fmaxf(bf2f(u.x) + bc.x, 0.f);
        v.y = fmaxf(bf2f(u.y) + bc.y, 0.f);
        v.z = fmaxf(bf2f(u.z) + bc.z, 0.f);
        v.w = fmaxf(bf2f(u.w) + bc.w, 0.f);
        ((float4*)buf)[lane] = v;
        int r0 = 2 * half;
        const float4* bx0 = (const float4*)(buf + r0 * 64);
        const float4* bx1 = (const float4*)(buf + (r0 + 1) * 64);
        float a0 = 0.f, a1 = 0.f;
#pragma unroll
        for (int j = 0; j < 16; ++j) {
            float4 x0 = bx0[j], x1 = bx1[j];
            float w0 = wv[4 * j], w1 = wv[4 * j + 1], w2 = wv[4 * j + 2], w3 = wv[4 * j + 3];
            a0 += x0.x * w0 + x0.y * w1 + x0.z * w2 + x0.w * w3;
            a1 += x1.x * w0 + x1.y * w1 + x1.z * w2 + x1.w * w3;
        }
        int n0 = g0 + r0;
        if (n0 < N)     hws[(size_t)n0 * C2 + c]       = f2bf(dinv[n0] * a0);
        if (n0 + 1 < N) hws[(size_t)(n0 + 1) * C2 + c] = f2bf(dinv[n0 + 1] * a1);
    }
}

// ---- g2pool: edge-parallel layer-2 aggregation + fused mean-pool ----
__global__ __launch_bounds__(256) void g2pool_kernel(
    const ushort2* __restrict__ hws2, const unsigned* __restrict__ ep,
    const int* __restrict__ bstart, const float* __restrict__ dinv,
    float* __restrict__ pooled, int N) {
    __shared__ float dl_dinv[BNODES];
    __shared__ float ps[32];
    int t = threadIdx.x;
    int b = blockIdx.x >> 1;
    int part = blockIdx.x & 1;
    int nbase = b * BNODES;
    int nloc = min(BNODES, N - nbase);
    if (t < 32) ps[t] = 0.f;
    if (t < BNODES) dl_dinv[t] = (t < nloc) ? dinv[nbase + t] : 0.f;
    __syncthreads();
    int es = bstart[b], ee = bstart[b + 1];
    int len = ee - es;
    int e_lo = es + ((len * part) >> 1);
    int e_hi = es + ((len * (part + 1)) >> 1);
    int lane = t & 63;
    int slot = t >> 4;   // 0..15
    int c2 = t & 15;
    float p0 = 0.f, p1 = 0.f;
    for (int e = e_lo + slot * 8; e < e_hi; e += 128) {
        int m = min(8, e_hi - e);
        int idx = e + (c2 & 7);
        unsigned ent = (idx < e_hi) ? ep[idx] : 0u;
#pragma unroll
        for (int j = 0; j < 8; ++j) {
            unsigned ej = __shfl(ent, (lane & 48) | j);
            if (j < m) {
                ushort2 v = hws2[(size_t)(ej & 0x1FFFFu) * 16 + c2];
                float dd = dl_dinv[ej >> 17];
                p0 += dd * bf2f(v.x);
                p1 += dd * bf2f(v.y);
            }
        }
    }
    if (part == 0) {
        for (int r = t >> 4; r < nloc; r += 16) {
            float di = dl_dinv[r];
            ushort2 sv = hws2[(size_t)(nbase + r) * 16 + c2];
            p0 += di * di * bf2f(sv.x);
            p1 += di * di * bf2f(sv.y);
        }
    }
    p0 += __shfl_down(p0, 32); p1 += __shfl_down(p1, 32);
    p0 += __shfl_down(p0, 16); p1 += __shfl_down(p1, 16);
    if (lane < 16) {
        atomicAdd(&ps[2 * c2], p0);
        atomicAdd(&ps[2 * c2 + 1], p1);
    }
    __syncthreads();
    if (t < 32) atomicAdd(&pooled[t], ps[t]);
}

// ---- final: mean + b2, log_softmax over 32 classes ----
__global__ void final_kernel(const float* __restrict__ pooled,
                             const float* __restrict__ b2, int N,
                             float* __restrict__ out) {
    int c = threadIdx.x & 31;
    float v = pooled[c] / (float)N + b2[c];
    float m = v;
    for (int off = 16; off; off >>= 1) m = fmaxf(m, __shfl_xor(m, off));
    float s = __expf(v - m);
    for (int off = 16; off; off >>= 1) s += __shfl_xor(s, off);
    if (threadIdx.x < 32) out[c] = v - m - logf(s);
}

extern "C" void kernel_launch(void* const* d_in, const int* in_sizes, int n_in,
                              void* d_out, int out_size, void* d_ws, size_t ws_size,
                              hipStream_t stream) {
    const float* x  = (const float*)d_in[0];
    const int*   ei = (const int*)d_in[1];
    const float* W1 = (const float*)d_in[2];
    const float* b1 = (const float*)d_in[3];
    const float* W2 = (const float*)d_in[4];
    const float* b2 = (const float*)d_in[5];
    float* out = (float*)d_out;

    int N = in_sizes[0] / C1;
    int E = in_sizes[1] / 2;
    const int* src = ei;
    const int* dst = ei + E;
    int NB = (N + BNODES - 1) / BNODES;   // 782
    int NC = (E + CHUNK - 1) / CHUNK;     // 196 (<= 256)

    char* ws = (char*)d_ws;
    size_t o = 0;
    auto alloc = [&](size_t bytes) { void* p = ws + o; o = (o + bytes + 255) & ~(size_t)255; return p; };
    unsigned*       btot    = (unsigned*)alloc((size_t)(NB + 1) * 4);
    int*            bstart  = (int*)alloc((size_t)(NB + 1) * 4);
    int*            startsT = (int*)alloc((size_t)NB * NC * 4);
    int*            countsT = (int*)alloc((size_t)NB * NC * 4);
    float*          dinv    = (float*)alloc((size_t)N * 4);
    int*            off     = (int*)alloc((size_t)(N + 1) * 4);
    float*          pooled  = (float*)alloc(32 * 4);
    unsigned*       binned  = (unsigned*)alloc((size_t)E * 4);
    unsigned*       ebkt    = (unsigned*)alloc((size_t)E * 4);
    unsigned short* xws     = (unsigned short*)alloc((size_t)N * C1 * 2);
    unsigned short* out1b   = (unsigned short*)alloc((size_t)N * C1 * 2);
    unsigned short* hws     = (unsigned short*)alloc((size_t)N * C2 * 2);

    hipMemsetAsync(btot, 0, (size_t)(NB + 1) * 4, stream);
    hipMemsetAsync(pooled, 0, 32 * 4, stream);

    binA_kernel<<<NC, 256, 0, stream>>>(src, dst, E, NB, NC, binned, startsT, countsT, btot);
    bscan_kernel<<<1, 256, 0, stream>>>(btot, bstart, NB);
    compact2_kernel<<<NB, 256, 0, stream>>>(binned, startsT, countsT, bstart, N, NC, E,
                                            ebkt, off, dinv);
    gemm1_kernel<<<1024, 256, 0, stream>>>(x, W1, dinv, xws, N);
    gather1_kernel<<<(N + 15) / 16, 256, 0, stream>>>((const ushort4*)xws, ebkt, off, dinv,
                                                      (ushort4*)out1b, N);
    gemm2_kernel<<<1024, 256, 0, stream>>>(out1b, W2, b1, dinv, hws, N);
    g2pool_kernel<<<NB * 2, 256, 0, stream>>>((const ushort2*)hws, ebkt, bstart, dinv,
                                              pooled, N);
    final_kernel<<<1, 64, 0, stream>>>(pooled, b2, N, out);
}

// Round 9
// 273.508 us; speedup vs baseline: 1.2198x; 1.1069x over previous
//
#include <hip/hip_runtime.h>
#include <math.h>

// GCN 2-layer, N nodes, E edges, 64 -> 64 -> 32 channels.
// R9: both GEMMs on MFMA (16x16x32 bf16, K=64 = 2 chained mfmas).
//  gemm1: A = bf16(x) from global (strided 16B loads), B = bf16(W1) in VGPRs,
//  epilogue scales by dinv -> xws bf16.
//  gemm2: A = bf16(relu(out1b + b1)) (input already bf16 in A-frag layout),
//  B = bf16(W2), epilogue dinv -> hws bf16.
// Front-end (binA/bscan/compact2), gather1, g2pool unchanged from R8.

#define C1 64
#define C2 32
#define CHUNK 8192
#define BNODES 128

typedef __attribute__((ext_vector_type(8))) short bf16x8;
typedef __attribute__((ext_vector_type(4))) float f32x4;

__device__ __forceinline__ unsigned short f2bf(float f) {
    unsigned u = __float_as_uint(f);
    u = (u + 0x7FFFu + ((u >> 16) & 1u)) >> 16;
    return (unsigned short)u;
}
__device__ __forceinline__ float bf2f(unsigned short u) {
    return __uint_as_float((unsigned)u << 16);
}

// ---- binA: per-chunk LDS counting sort by bucket (dst>>7). Coalesced IO. ----
__global__ __launch_bounds__(256) void binA_kernel(
    const int* __restrict__ src, const int* __restrict__ dst, int E, int NB, int NC,
    unsigned* __restrict__ binned, int* __restrict__ startsT,
    int* __restrict__ countsT, unsigned* __restrict__ btot) {
    __shared__ unsigned hist[1024];
    __shared__ unsigned scan[1024];
    __shared__ unsigned part[256];
    __shared__ unsigned stage[CHUNK];
    int t = threadIdx.x;
    int c = blockIdx.x;
    int e0 = c * CHUNK;
    int len = min(CHUNK, E - e0);
    for (int i = t; i < 1024; i += 256) hist[i] = 0;
    __syncthreads();
    for (int i = t; i < len; i += 256)
        atomicAdd(&hist[dst[e0 + i] >> 7], 1u);
    __syncthreads();
    unsigned v0 = hist[4 * t], v1 = hist[4 * t + 1], v2 = hist[4 * t + 2], v3 = hist[4 * t + 3];
    unsigned sum = v0 + v1 + v2 + v3;
    part[t] = sum;
    __syncthreads();
    for (int st = 1; st < 256; st <<= 1) {
        unsigned a = part[t];
        unsigned bl = (t >= st) ? part[t - st] : 0u;
        __syncthreads();
        part[t] = a + bl;
        __syncthreads();
    }
    unsigned base = part[t] - sum;
    scan[4 * t]     = base;
    scan[4 * t + 1] = base + v0;
    scan[4 * t + 2] = base + v0 + v1;
    scan[4 * t + 3] = base + v0 + v1 + v2;
    __syncthreads();
    for (int b = t; b < NB; b += 256) {
        unsigned cnt = hist[b];
        countsT[b * NC + c] = (int)cnt;
        startsT[b * NC + c] = e0 + (int)scan[b];
        if (cnt) atomicAdd(&btot[b], cnt);
    }
    for (int i = t; i < len; i += 256) {
        int s = src[e0 + i];
        int d = dst[e0 + i];
        unsigned pos = atomicAdd(&scan[d >> 7], 1u);
        stage[pos] = ((unsigned)(d & 127) << 17) | (unsigned)s;
    }
    __syncthreads();
    for (int i = t; i < len; i += 256) binned[e0 + i] = stage[i];
}

// ---- bscan: exclusive scan of per-bucket totals -> bstart[NB+1] ----
__global__ __launch_bounds__(256) void bscan_kernel(const unsigned* __restrict__ btot,
                                                    int* __restrict__ bstart, int NB) {
    __shared__ unsigned part[256];
    int t = threadIdx.x;
    unsigned v[4];
    unsigned sum = 0;
    for (int i = 0; i < 4; ++i) {
        int idx = 4 * t + i;
        v[i] = (idx < NB) ? btot[idx] : 0u;
        sum += v[i];
    }
    part[t] = sum;
    __syncthreads();
    for (int st = 1; st < 256; st <<= 1) {
        unsigned a = part[t];
        unsigned bl = (t >= st) ? part[t - st] : 0u;
        __syncthreads();
        part[t] = a + bl;
        __syncthreads();
    }
    unsigned run = part[t] - sum;
    for (int i = 0; i < 4; ++i) {
        int idx = 4 * t + i;
        if (idx < NB) bstart[idx] = (int)run;
        run += v[i];
    }
    if (t == 255) bstart[NB] = (int)run;
}

// ---- compact2: per-bucket per-node counting sort; fused deg->dinv + off ----
__global__ __launch_bounds__(256) void compact2_kernel(
    const unsigned* __restrict__ binned, const int* __restrict__ startsT,
    const int* __restrict__ countsT, const int* __restrict__ bstart,
    int N, int NC, int E, unsigned* __restrict__ ebkt, int* __restrict__ off,
    float* __restrict__ dinv) {
    __shared__ unsigned cnt[BNODES];
    __shared__ unsigned sc[BNODES];
    __shared__ unsigned cur[BNODES];
    __shared__ int sS[256], sC[256];
    int t = threadIdx.x;
    int b = blockIdx.x;
    if (t < BNODES) cnt[t] = 0;
    if (t < NC) { sS[t] = startsT[b * NC + t]; sC[t] = countsT[b * NC + t]; }
    __syncthreads();
    int lane = t & 63, w = t >> 6;
    for (int c = w; c < NC; c += 4) {
        int s0 = sS[c], len = sC[c];
        for (int o = lane; o < len; o += 64)
            atomicAdd(&cnt[binned[s0 + o] >> 17], 1u);
    }
    __syncthreads();
    if (t < BNODES) sc[t] = cnt[t];
    __syncthreads();
    for (int st = 1; st < BNODES; st <<= 1) {
        unsigned v = 0;
        if (t < BNODES) { v = sc[t]; if (t >= st) v += sc[t - st]; }
        __syncthreads();
        if (t < BNODES) sc[t] = v;
        __syncthreads();
    }
    int dbase = bstart[b];
    if (t < BNODES) {
        unsigned excl = sc[t] - cnt[t];
        cur[t] = excl;
        int n = b * BNODES + t;
        if (n < N) {
            off[n] = dbase + (int)excl;
            dinv[n] = rsqrtf((float)cnt[t] + 1.0f);
        }
    }
    if (b == 0 && t == 0) off[N] = E;
    __syncthreads();
    for (int c = w; c < NC; c += 4) {
        int s0 = sS[c], len = sC[c];
        for (int o = lane; o < len; o += 64) {
            unsigned ent = binned[s0 + o];
            unsigned pos = atomicAdd(&cur[ent >> 17], 1u);
            ebkt[dbase + (int)pos] = ent;  // keep dl bits
        }
    }
}

// ---- gemm1 (MFMA): xws = bf16(dinv * (x @ W1)) ----
// Wave handles 16-row tiles. A[m=lane&15][k=quad*8+j], B[k][n=lane&15],
// C: col=lane&15, row=quad*4+reg.
__global__ __launch_bounds__(256) void gemm1_kernel(
    const float* __restrict__ x, const float* __restrict__ W,
    const float* __restrict__ dinv, unsigned short* __restrict__ xws, int N) {
    int t = threadIdx.x;
    int lane = t & 63;
    int n16 = lane & 15;
    int quad = lane >> 4;
    // B fragments: b[cg][kh][j] = bf16(W[(kh*32+quad*8+j)*64 + cg*16 + n16])
    bf16x8 bf[4][2];
#pragma unroll
    for (int cg = 0; cg < 4; ++cg)
#pragma unroll
        for (int kh = 0; kh < 2; ++kh)
#pragma unroll
            for (int j = 0; j < 8; ++j)
                bf[cg][kh][j] = (short)f2bf(W[(kh * 32 + quad * 8 + j) * 64 + cg * 16 + n16]);
    int tiles = (N + 15) >> 4;
    int wave = (blockIdx.x * blockDim.x + t) >> 6;
    int nw = (gridDim.x * blockDim.x) >> 6;
    for (int tile = wave; tile < tiles; tile += nw) {
        int nbase = tile << 4;
        int m = nbase + n16;  // A row this lane loads
        bf16x8 af[2];
        if (m < N) {
            const float* xr = x + (size_t)m * C1;
#pragma unroll
            for (int kh = 0; kh < 2; ++kh) {
                float4 p0 = *(const float4*)(xr + kh * 32 + quad * 8);
                float4 p1 = *(const float4*)(xr + kh * 32 + quad * 8 + 4);
                af[kh][0] = (short)f2bf(p0.x); af[kh][1] = (short)f2bf(p0.y);
                af[kh][2] = (short)f2bf(p0.z); af[kh][3] = (short)f2bf(p0.w);
                af[kh][4] = (short)f2bf(p1.x); af[kh][5] = (short)f2bf(p1.y);
                af[kh][6] = (short)f2bf(p1.z); af[kh][7] = (short)f2bf(p1.w);
            }
        } else {
            af[0] = (bf16x8)(short)0;
            af[1] = (bf16x8)(short)0;
        }
        f32x4 acc[4];
#pragma unroll
        for (int cg = 0; cg < 4; ++cg) {
            acc[cg] = (f32x4)0.f;
            acc[cg] = __builtin_amdgcn_mfma_f32_16x16x32_bf16(af[0], bf[cg][0], acc[cg], 0, 0, 0);
            acc[cg] = __builtin_amdgcn_mfma_f32_16x16x32_bf16(af[1], bf[cg][1], acc[cg], 0, 0, 0);
        }
        int r0 = nbase + quad * 4;
        float4 dv = make_float4(0.f, 0.f, 0.f, 0.f);
        if (r0 + 3 < N) dv = *(const float4*)(dinv + r0);
        else {
            if (r0 < N) dv.x = dinv[r0];
            if (r0 + 1 < N) dv.y = dinv[r0 + 1];
            if (r0 + 2 < N) dv.z = dinv[r0 + 2];
            if (r0 + 3 < N) dv.w = dinv[r0 + 3];
        }
        float dvr[4] = {dv.x, dv.y, dv.z, dv.w};
#pragma unroll
        for (int reg = 0; reg < 4; ++reg) {
            int row = r0 + reg;
            if (row < N) {
                unsigned short* orow = xws + (size_t)row * C1 + n16;
#pragma unroll
                for (int cg = 0; cg < 4; ++cg)
                    orow[cg * 16] = f2bf(dvr[reg] * acc[cg][reg]);
            }
        }
    }
}

// ---- gather1: quarter-slot per node; 16-edge batches, ushort4 row loads ----
__global__ __launch_bounds__(256) void gather1_kernel(
    const ushort4* __restrict__ xws4, const unsigned* __restrict__ ep,
    const int* __restrict__ off, const float* __restrict__ dinv,
    ushort4* __restrict__ out1b, int N) {
    int t = threadIdx.x;
    int lane = t & 63;
    int c4 = t & 15;
    int n = (blockIdx.x * 256 + t) >> 4;  // slot == node
    if (n >= N) return;
    int e0 = off[n], e1 = off[n + 1];
    float a0 = 0.f, a1 = 0.f, a2 = 0.f, a3 = 0.f;
    for (int e = e0; e < e1; e += 16) {
        int m = e1 - e;
        int idx = e + c4;
        unsigned ent = (idx < e1) ? ep[idx] : 0u;
#pragma unroll
        for (int j = 0; j < 16; ++j) {
            unsigned ej = __shfl(ent, (lane & 48) | j);
            if (j < m) {
                ushort4 v = xws4[(size_t)(ej & 0x1FFFFu) * 16 + c4];
                a0 += bf2f(v.x);
                a1 += bf2f(v.y);
                a2 += bf2f(v.z);
                a3 += bf2f(v.w);
            }
        }
    }
    float di = dinv[n];
    ushort4 sv = xws4[(size_t)n * 16 + c4];
    ushort4 o;
    o.x = f2bf(di * (a0 + di * bf2f(sv.x)));
    o.y = f2bf(di * (a1 + di * bf2f(sv.y)));
    o.z = f2bf(di * (a2 + di * bf2f(sv.z)));
    o.w = f2bf(di * (a3 + di * bf2f(sv.w)));
    out1b[(size_t)n * 16 + c4] = o;
}

// ---- gemm2 (MFMA): hws = bf16(dinv * (relu(out1b + b1) @ W2)) ----
__global__ __launch_bounds__(256) void gemm2_kernel(
    const unsigned short* __restrict__ out1b, const float* __restrict__ W2,
    const float* __restrict__ b1, const float* __restrict__ dinv,
    unsigned short* __restrict__ hws, int N) {
    int t = threadIdx.x;
    int lane = t & 63;
    int n16 = lane & 15;
    int quad = lane >> 4;
    bf16x8 bf[2][2];
#pragma unroll
    for (int cg = 0; cg < 2; ++cg)
#pragma unroll
        for (int kh = 0; kh < 2; ++kh)
#pragma unroll
            for (int j = 0; j < 8; ++j)
                bf[cg][kh][j] = (short)f2bf(W2[(kh * 32 + quad * 8 + j) * 32 + cg * 16 + n16]);
    float bb[2][8];
#pragma unroll
    for (int kh = 0; kh < 2; ++kh)
#pragma unroll
        for (int j = 0; j < 8; ++j)
            bb[kh][j] = b1[kh * 32 + quad * 8 + j];
    int tiles = (N + 15) >> 4;
    int wave = (blockIdx.x * blockDim.x + t) >> 6;
    int nw = (gridDim.x * blockDim.x) >> 6;
    for (int tile = wave; tile < tiles; tile += nw) {
        int nbase = tile << 4;
        int m = nbase + n16;
        bf16x8 af[2];
        if (m < N) {
            const unsigned short* hr = out1b + (size_t)m * C1;
#pragma unroll
            for (int kh = 0; kh < 2; ++kh) {
                ushort4 q0 = *(const ushort4*)(hr + kh * 32 + quad * 8);
                ushort4 q1 = *(const ushort4*)(hr + kh * 32 + quad * 8 + 4);
                af[kh][0] = (short)f2bf(fmaxf(bf2f(q0.x) + bb[kh][0], 0.f));
                af[kh][1] = (short)f2bf(fmaxf(bf2f(q0.y) + bb[kh][1], 0.f));
                af[kh][2] = (short)f2bf(fmaxf(bf2f(q0.z) + bb[kh][2], 0.f));
                af[kh][3] = (short)f2bf(fmaxf(bf2f(q0.w) + bb[kh][3], 0.f));
                af[kh][4] = (short)f2bf(fmaxf(bf2f(q1.x) + bb[kh][4], 0.f));
                af[kh][5] = (short)f2bf(fmaxf(bf2f(q1.y) + bb[kh][5], 0.f));
                af[kh][6] = (short)f2bf(fmaxf(bf2f(q1.z) + bb[kh][6], 0.f));
                af[kh][7] = (short)f2bf(fmaxf(bf2f(q1.w) + bb[kh][7], 0.f));
            }
        } else {
            af[0] = (bf16x8)(short)0;
            af[1] = (bf16x8)(short)0;
        }
        f32x4 acc[2];
#pragma unroll
        for (int cg = 0; cg < 2; ++cg) {
            acc[cg] = (f32x4)0.f;
            acc[cg] = __builtin_amdgcn_mfma_f32_16x16x32_bf16(af[0], bf[cg][0], acc[cg], 0, 0, 0);
            acc[cg] = __builtin_amdgcn_mfma_f32_16x16x32_bf16(af[1], bf[cg][1], acc[cg], 0, 0, 0);
        }
        int r0 = nbase + quad * 4;
#pragma unroll
        for (int reg = 0; reg < 4; ++reg) {
            int row = r0 + reg;
            if (row < N) {
                float dvr = dinv[row];
                unsigned short* orow = hws + (size_t)row * C2 + n16;
                orow[0]  = f2bf(dvr * acc[0][reg]);
                orow[16] = f2bf(dvr * acc[1][reg]);
            }
        }
    }
}

// ---- g2pool: edge-parallel layer-2 aggregation + fused mean-pool ----
__global__ __launch_bounds__(256) void g2pool_kernel(
    const ushort2* __restrict__ hws2, const unsigned* __restrict__ ep,
    const int* __restrict__ bstart, const float* __restrict__ dinv,
    float* __restrict__ pooled, int N) {
    __shared__ float dl_dinv[BNODES];
    __shared__ float ps[32];
    int t = threadIdx.x;
    int b = blockIdx.x >> 1;
    int part = blockIdx.x & 1;
    int nbase = b * BNODES;
    int nloc = min(BNODES, N - nbase);
    if (t < 32) ps[t] = 0.f;
    if (t < BNODES) dl_dinv[t] = (t < nloc) ? dinv[nbase + t] : 0.f;
    __syncthreads();
    int es = bstart[b], ee = bstart[b + 1];
    int len = ee - es;
    int e_lo = es + ((len * part) >> 1);
    int e_hi = es + ((len * (part + 1)) >> 1);
    int lane = t & 63;
    int slot = t >> 4;
    int c2 = t & 15;
    float p0 = 0.f, p1 = 0.f;
    for (int e = e_lo + slot * 8; e < e_hi; e += 128) {
        int m = min(8, e_hi - e);
        int idx = e + (c2 & 7);
        unsigned ent = (idx < e_hi) ? ep[idx] : 0u;
#pragma unroll
        for (int j = 0; j < 8; ++j) {
            unsigned ej = __shfl(ent, (lane & 48) | j);
            if (j < m) {
                ushort2 v = hws2[(size_t)(ej & 0x1FFFFu) * 16 + c2];
                float dd = dl_dinv[ej >> 17];
                p0 += dd * bf2f(v.x);
                p1 += dd * bf2f(v.y);
            }
        }
    }
    if (part == 0) {
        for (int r = t >> 4; r < nloc; r += 16) {
            float di = dl_dinv[r];
            ushort2 sv = hws2[(size_t)(nbase + r) * 16 + c2];
            p0 += di * di * bf2f(sv.x);
            p1 += di * di * bf2f(sv.y);
        }
    }
    p0 += __shfl_down(p0, 32); p1 += __shfl_down(p1, 32);
    p0 += __shfl_down(p0, 16); p1 += __shfl_down(p1, 16);
    if (lane < 16) {
        atomicAdd(&ps[2 * c2], p0);
        atomicAdd(&ps[2 * c2 + 1], p1);
    }
    __syncthreads();
    if (t < 32) atomicAdd(&pooled[t], ps[t]);
}

// ---- final: mean + b2, log_softmax over 32 classes ----
__global__ void final_kernel(const float* __restrict__ pooled,
                             const float* __restrict__ b2, int N,
                             float* __restrict__ out) {
    int c = threadIdx.x & 31;
    float v = pooled[c] / (float)N + b2[c];
    float m = v;
    for (int off = 16; off; off >>= 1) m = fmaxf(m, __shfl_xor(m, off));
    float s = __expf(v - m);
    for (int off = 16; off; off >>= 1) s += __shfl_xor(s, off);
    if (threadIdx.x < 32) out[c] = v - m - logf(s);
}

extern "C" void kernel_launch(void* const* d_in, const int* in_sizes, int n_in,
                              void* d_out, int out_size, void* d_ws, size_t ws_size,
                              hipStream_t stream) {
    const float* x  = (const float*)d_in[0];
    const int*   ei = (const int*)d_in[1];
    const float* W1 = (const float*)d_in[2];
    const float* b1 = (const float*)d_in[3];
    const float* W2 = (const float*)d_in[4];
    const float* b2 = (const float*)d_in[5];
    float* out = (float*)d_out;

    int N = in_sizes[0] / C1;
    int E = in_sizes[1] / 2;
    const int* src = ei;
    const int* dst = ei + E;
    int NB = (N + BNODES - 1) / BNODES;   // 782
    int NC = (E + CHUNK - 1) / CHUNK;     // 196 (<= 256)

    char* ws = (char*)d_ws;
    size_t o = 0;
    auto alloc = [&](size_t bytes) { void* p = ws + o; o = (o + bytes + 255) & ~(size_t)255; return p; };
    unsigned*       btot    = (unsigned*)alloc((size_t)(NB + 1) * 4);
    int*            bstart  = (int*)alloc((size_t)(NB + 1) * 4);
    int*            startsT = (int*)alloc((size_t)NB * NC * 4);
    int*            countsT = (int*)alloc((size_t)NB * NC * 4);
    float*          dinv    = (float*)alloc((size_t)N * 4);
    int*            off     = (int*)alloc((size_t)(N + 1) * 4);
    float*          pooled  = (float*)alloc(32 * 4);
    unsigned*       binned  = (unsigned*)alloc((size_t)E * 4);
    unsigned*       ebkt    = (unsigned*)alloc((size_t)E * 4);
    unsigned short* xws     = (unsigned short*)alloc((size_t)N * C1 * 2);
    unsigned short* out1b   = (unsigned short*)alloc((size_t)N * C1 * 2);
    unsigned short* hws     = (unsigned short*)alloc((size_t)N * C2 * 2);

    hipMemsetAsync(btot, 0, (size_t)(NB + 1) * 4, stream);
    hipMemsetAsync(pooled, 0, 32 * 4, stream);

    binA_kernel<<<NC, 256, 0, stream>>>(src, dst, E, NB, NC, binned, startsT, countsT, btot);
    bscan_kernel<<<1, 256, 0, stream>>>(btot, bstart, NB);
    compact2_kernel<<<NB, 256, 0, stream>>>(binned, startsT, countsT, bstart, N, NC, E,
                                            ebkt, off, dinv);
    gemm1_kernel<<<256, 256, 0, stream>>>(x, W1, dinv, xws, N);
    gather1_kernel<<<(N + 15) / 16, 256, 0, stream>>>((const ushort4*)xws, ebkt, off, dinv,
                                                      (ushort4*)out1b, N);
    gemm2_kernel<<<256, 256, 0, stream>>>(out1b, W2, b1, dinv, hws, N);
    g2pool_kernel<<<NB * 2, 256, 0, stream>>>((const ushort2*)hws, ebkt, bstart, dinv,
                                              pooled, N);
    final_kernel<<<1, 64, 0, stream>>>(pooled, b2, N, out);
}